// Round 5
// baseline (710.495 us; speedup 1.0000x reference)
//
#include <hip/hip_runtime.h>

typedef _Float16 f16;
typedef _Float16 f16x8 __attribute__((ext_vector_type(8)));
typedef _Float16 f16x4 __attribute__((ext_vector_type(4)));
typedef float    f32x4 __attribute__((ext_vector_type(4)));

#define H  128
#define G3 384
#define AH 36

__device__ __forceinline__ float sigmoidf_(float x){ return 1.f/(1.f+__expf(-x)); }
__device__ __forceinline__ float tanhf_(float x){ return 2.f/(1.f+__expf(-2.f*x)) - 1.f; }

// LDS-only barrier (global prefetch loads stay in flight across it)
__device__ __forceinline__ void lds_sync(){
  asm volatile("s_waitcnt lgkmcnt(0)" ::: "memory");
  __builtin_amdgcn_s_barrier();
  asm volatile("" ::: "memory");
}

// swizzled accessor for LDS tiles with 256B rows (proven R1/R3)
__device__ __forceinline__ f16* tptr(f16* base, int row, int kbyte){
  return (f16*)((char*)base + row*256 + (kbyte ^ ((row & 7) << 4)));
}
__device__ __forceinline__ const f16* tptrc(const f16* base, int row, int kbyte){
  return (const f16*)((const char*)base + row*256 + (kbyte ^ ((row & 7) << 4)));
}

// ---------------- prep ----------------
__global__ void prep_weights(const float* __restrict__ a, const float* __restrict__ b,
                             const float* __restrict__ c, const float* __restrict__ d,
                             f16* __restrict__ dst)
{
  int i = blockIdx.x * 256 + threadIdx.x;
  if (i >= 4 * G3 * H) return;
  int m = i / (G3 * H), j = i % (G3 * H);
  const float* s = (m == 0) ? a : (m == 1) ? b : (m == 2) ? c : d;
  dst[i] = (f16)s[j];
}

__global__ void prep_len(const int* __restrict__ mask, int* __restrict__ len, int T, int B)
{
  int b = blockIdx.x * 256 + threadIdx.x;
  if (b >= B) return;
  int s = 0;
  for (int t = 0; t < T; ++t) s += (mask[(size_t)b * T + t] > 0);
  len[b] = s;
}

// ---------------- gx GEMM: gx[t][bblk][16][3H] = x @ Wih^T + bias ----------------
// grid (Bblk, 8), 512 thr. Wave w owns gate cols [48w,48w+48) (3 MFMA tiles),
// weight A-frags resident (48 VGPR). Depth-1 input prefetch ping-pong.
template<bool F16IN>
__global__ __launch_bounds__(512, 2)
void gx_gemm(const float* __restrict__ xf32, const f16* __restrict__ xf16,
             const f16*  __restrict__ Wg,    // [3H][H] f16
             const float* __restrict__ bias, // [3H]
             f16* __restrict__ gx,           // [T][Bblk][16][3H]
             int T, int Bblk)
{
  const int tid = threadIdx.x, w = tid >> 6, l = tid & 63, l16 = l & 15, lhi = l >> 4;
  const int bblk = blockIdx.x, b0 = bblk * 16;
  const int nch = gridDim.y;
  const int tchunk = (T + nch - 1) / nch;
  const int T0 = blockIdx.y * tchunk;
  if (T0 >= T) return;
  const int T1 = (T0 + tchunk < T) ? T0 + tchunk : T;
  const int cg0 = 48 * w;

  f16x8 afr[3][4];
  #pragma unroll
  for (int tile = 0; tile < 3; ++tile)
    #pragma unroll
    for (int q = 0; q < 4; ++q)
      afr[tile][q] = *(const f16x8*)(Wg + (cg0 + tile*16 + l16)*H + q*32 + lhi*8);
  #pragma unroll
  for (int tile = 0; tile < 3; ++tile)
    #pragma unroll
    for (int q = 0; q < 4; ++q)
      asm volatile("" : "+v"(afr[tile][q]));

  f32x4 bv[3];
  #pragma unroll
  for (int tile = 0; tile < 3; ++tile)
    bv[tile] = *(const f32x4*)(bias + cg0 + tile*16 + lhi*4);

  const size_t rbase = ((size_t)(b0 + l16) * T) * H + lhi * 8;

  f32x4 Ar[8], Br[8];   // f32 input raw ping-pong
  f16x8 Ah[4], Bh[4];   // f16 input raw ping-pong

  if constexpr (F16IN) {
    #pragma unroll
    for (int q = 0; q < 4; ++q)
      Ah[q] = *(const f16x8*)(xf16 + rbase + (size_t)T0*H + q*32);
  } else {
    #pragma unroll
    for (int q = 0; q < 4; ++q) {
      Ar[2*q]   = *(const f32x4*)(xf32 + rbase + (size_t)T0*H + q*32);
      Ar[2*q+1] = *(const f32x4*)(xf32 + rbase + (size_t)T0*H + q*32 + 4);
    }
  }

#define GBODY(CUR, NXT, targ_)                                                 \
  {                                                                            \
    const int t5 = (targ_);                                                    \
    if (t5 + 1 < T1) {                                                         \
      if constexpr (F16IN) {                                                   \
        _Pragma("unroll")                                                      \
        for (int q = 0; q < 4; ++q)                                            \
          NXT##h[q] = *(const f16x8*)(xf16 + rbase + (size_t)(t5+1)*H + q*32); \
      } else {                                                                 \
        _Pragma("unroll")                                                      \
        for (int q = 0; q < 4; ++q) {                                          \
          NXT##r[2*q]   = *(const f32x4*)(xf32 + rbase + (size_t)(t5+1)*H + q*32);     \
          NXT##r[2*q+1] = *(const f32x4*)(xf32 + rbase + (size_t)(t5+1)*H + q*32 + 4); \
        }                                                                      \
      }                                                                        \
    }                                                                          \
    f16x8 bq_[4];                                                              \
    if constexpr (F16IN) {                                                     \
      _Pragma("unroll")                                                        \
      for (int q = 0; q < 4; ++q) bq_[q] = CUR##h[q];                          \
    } else {                                                                   \
      _Pragma("unroll")                                                        \
      for (int q = 0; q < 4; ++q) {                                            \
        _Pragma("unroll")                                                      \
        for (int j = 0; j < 4; ++j) {                                          \
          bq_[q][j]   = (f16)CUR##r[2*q][j];                                   \
          bq_[q][4+j] = (f16)CUR##r[2*q+1][j];                                 \
        }                                                                      \
      }                                                                        \
    }                                                                          \
    f32x4 cc0 = bv[0], cc1 = bv[1], cc2 = bv[2];                               \
    _Pragma("unroll")                                                          \
    for (int q = 0; q < 4; ++q) {                                              \
      cc0 = __builtin_amdgcn_mfma_f32_16x16x32_f16(afr[0][q], bq_[q], cc0, 0,0,0); \
      cc1 = __builtin_amdgcn_mfma_f32_16x16x32_f16(afr[1][q], bq_[q], cc1, 0,0,0); \
      cc2 = __builtin_amdgcn_mfma_f32_16x16x32_f16(afr[2][q], bq_[q], cc2, 0,0,0); \
    }                                                                          \
    const size_t gb_ = ((size_t)t5*Bblk + bblk)*(size_t)(16*G3) + (size_t)l16*G3 + cg0 + lhi*4; \
    { f16x4 o = {(f16)cc0[0],(f16)cc0[1],(f16)cc0[2],(f16)cc0[3]}; *(f16x4*)(gx + gb_)      = o; } \
    { f16x4 o = {(f16)cc1[0],(f16)cc1[1],(f16)cc1[2],(f16)cc1[3]}; *(f16x4*)(gx + gb_ + 16) = o; } \
    { f16x4 o = {(f16)cc2[0],(f16)cc2[1],(f16)cc2[2],(f16)cc2[3]}; *(f16x4*)(gx + gb_ + 32) = o; } \
  }

  int t = T0;
  for (;;) {
    GBODY(A, B, t); ++t; if (t >= T1) break;
    GBODY(B, A, t); ++t; if (t >= T1) break;
  }
#undef GBODY
}

// ---------------- scan: only the recurrence (12 MFMA/step) ----------------
// gx (input gates, bias folded) read depth-2 into registers; h via swizzled LDS.
template<bool AUG>
__global__ __launch_bounds__(512, 2)
void scan_kernel(const f16*  __restrict__ gxin,  // [T][Bblk][16][3H]
                 const f16*  __restrict__ Whh,   // [3H][H] f16
                 const float* __restrict__ bhh,  // [3H]
                 const float* __restrict__ att,  // [B,T] (AUG)
                 const int*  __restrict__ len,   // [B]   (AUG)
                 f16*        __restrict__ histo, // [B,T,H] f16 (GRU)
                 float*      __restrict__ outp,  // [B,H]       (AUG)
                 int T, int Bblk)
{
  __shared__ f16 hs[2][16 * H];

  const int tid = threadIdx.x, w = tid >> 6, l = tid & 63, l16 = l & 15, lhi = l >> 4;
  const int blk = blockIdx.x, b0 = blk * 16, colb = w * 16, c4 = colb + lhi * 4;

  f16x8 whhF[3][4];
  #pragma unroll
  for (int g = 0; g < 3; ++g)
    #pragma unroll
    for (int q = 0; q < 4; ++q)
      whhF[g][q] = *(const f16x8*)(Whh + (g*H + colb + l16)*H + q*32 + lhi*8);
  #pragma unroll
  for (int g = 0; g < 3; ++g)
    #pragma unroll
    for (int q = 0; q < 4; ++q)
      asm volatile("" : "+v"(whhF[g][q]));

  const f32x4 bR = *(const f32x4*)(bhh + c4);
  const f32x4 bZ = *(const f32x4*)(bhh + H + c4);
  const f32x4 bN = *(const f32x4*)(bhh + 2*H + c4);

  float hold[4] = {0.f, 0.f, 0.f, 0.f};
  int len_l = 0;
  if (AUG) len_l = len[b0 + l16];

  const size_t gstep = (size_t)Bblk * 16 * G3;
  const size_t grow  = ((size_t)blk * 16 + l16) * G3 + c4;

  { f16x4 z = {(f16)0,(f16)0,(f16)0,(f16)0};
    *(f16x4*)tptr(hs[0], tid >> 5, (tid & 31) * 8) = z; }

  f16x4 Pa[3], Pb[3];
  #pragma unroll
  for (int g = 0; g < 3; ++g) Pa[g] = *(const f16x4*)(gxin + grow + g*H);
  if (T > 1)
    #pragma unroll
    for (int g = 0; g < 3; ++g) Pb[g] = *(const f16x4*)(gxin + gstep + grow + g*H);
  float Aa = 0.f, Ab = 0.f;
  if (AUG) {
    Aa = att[(size_t)(b0 + l16) * T];
    if (T > 1) Ab = att[(size_t)(b0 + l16) * T + 1];
  }
  lds_sync();

#define SSTEP(targ_, PW, AW)                                                   \
  {                                                                            \
    const int t5 = (targ_);                                                    \
    if (t5 < T) {                                                              \
      const int cur_ = t5 & 1, nxt_ = cur_ ^ 1;                                \
      float xr_[4], xz_[4], xn_[4];                                            \
      _Pragma("unroll")                                                        \
      for (int i = 0; i < 4; ++i) {                                            \
        xr_[i] = (float)PW[0][i]; xz_[i] = (float)PW[1][i]; xn_[i] = (float)PW[2][i]; \
      }                                                                        \
      float at_ = 0.f;                                                         \
      if (AUG) at_ = AW;                                                       \
      if (t5 + 2 < T) {                                                        \
        _Pragma("unroll")                                                      \
        for (int g = 0; g < 3; ++g)                                            \
          PW[g] = *(const f16x4*)(gxin + (size_t)(t5+2)*gstep + grow + g*H);   \
        if (AUG) AW = att[(size_t)(b0 + l16)*T + t5 + 2];                      \
      }                                                                        \
      f16x8 hbf[4];                                                            \
      _Pragma("unroll")                                                        \
      for (int q = 0; q < 4; ++q)                                              \
        hbf[q] = *(const f16x8*)tptrc((const f16*)hs[cur_], l16, q*64 + lhi*16); \
      f32x4 aR = bR, aZ = bZ, aN = bN;                                         \
      _Pragma("unroll")                                                        \
      for (int q = 0; q < 4; ++q) {                                            \
        aR = __builtin_amdgcn_mfma_f32_16x16x32_f16(whhF[0][q], hbf[q], aR, 0,0,0); \
        aZ = __builtin_amdgcn_mfma_f32_16x16x32_f16(whhF[1][q], hbf[q], aZ, 0,0,0); \
        aN = __builtin_amdgcn_mfma_f32_16x16x32_f16(whhF[2][q], hbf[q], aN, 0,0,0); \
      }                                                                        \
      float hn_[4];                                                            \
      _Pragma("unroll")                                                        \
      for (int i = 0; i < 4; ++i) {                                            \
        float r = sigmoidf_(xr_[i] + aR[i]);                                   \
        float z = sigmoidf_(xz_[i] + aZ[i]);                                   \
        float n = tanhf_(xn_[i] + r * aN[i]);                                  \
        float h;                                                               \
        if (AUG) { float u = z * at_; h = hold[i] + u * (n - hold[i]); }       \
        else     { h = n + z * (hold[i] - n); }                                \
        hold[i] = h; hn_[i] = h;                                               \
      }                                                                        \
      f16x4 hv = {(f16)hn_[0], (f16)hn_[1], (f16)hn_[2], (f16)hn_[3]};         \
      *(f16x4*)tptr(hs[nxt_], l16, 2 * c4) = hv;                               \
      if (!AUG) {                                                              \
        *(f16x4*)(histo + ((size_t)(b0 + l16)*T + t5)*H + c4) = hv;            \
      } else if (t5 == len_l - 1) {                                            \
        f32x4 ov = {hn_[0], hn_[1], hn_[2], hn_[3]};                           \
        *(f32x4*)(outp + (size_t)(b0 + l16)*H + c4) = ov;                      \
      }                                                                        \
      lds_sync();                                                              \
    }                                                                          \
  }

  for (int t = 0; t < T; t += 2) {
    SSTEP(t,     Pa, Aa)
    SSTEP(t + 1, Pb, Ab)
  }
#undef SSTEP
}

// ---------------- DIN attention (MFMA version) ----------------
// Wq = (W1b - W1c + q⊙W1d) as f16 in LDS (swizzled); hidden = Wq·h^T via MFMA.
__global__ __launch_bounds__(256)
void attn_kernel(const float* __restrict__ query,
                 const f16*   __restrict__ hist,
                 const int*   __restrict__ mask,
                 const float* __restrict__ W1, const float* __restrict__ b1,
                 const float* __restrict__ W2, const float* __restrict__ b2,
                 float* __restrict__ attv, int T)
{
  __shared__ float qs[H];
  __shared__ f16   WqH[48 * H];       // 48 rows (36 used) x 256B, swizzled
  __shared__ float qcp[48], w2p[48];
  __shared__ float logitsS[224];
  __shared__ float red[256];

  const int tid = threadIdx.x, b = blockIdx.x;
  const int w = tid >> 6, l = tid & 63, l16 = l & 15, lhi = l >> 4;

  if (tid < H) qs[tid] = query[b * H + tid];
  if (tid < 48) w2p[tid] = (tid < AH) ? W2[tid] : 0.f;
  __syncthreads();

  for (int i = tid; i < 48 * H; i += 256) {
    int u = i >> 7, k = i & (H - 1);
    float v = 0.f;
    if (u < AH) {
      const float* r = W1 + u * 4 * H;
      v = r[H + k] - r[2*H + k] + qs[k] * r[3*H + k];
    }
    *tptr((f16*)WqH, u, 2 * k) = (f16)v;
  }
  if (tid < 48) {
    float s = 0.f;
    if (tid < AH) {
      const float* r = W1 + tid * 4 * H;
      s = b1[tid];
      for (int k = 0; k < H; ++k) s += qs[k] * (r[k] + r[2*H + k]);
    }
    qcp[tid] = s;
  }
  __syncthreads();

  const f32x4 qcv0 = *(const f32x4*)&qcp[lhi*4];
  const f32x4 qcv1 = *(const f32x4*)&qcp[16 + lhi*4];
  const f32x4 qcv2 = *(const f32x4*)&qcp[32 + lhi*4];
  const f32x4 w2v0 = *(const f32x4*)&w2p[lhi*4];
  const f32x4 w2v1 = *(const f32x4*)&w2p[16 + lhi*4];
  const f32x4 w2v2 = *(const f32x4*)&w2p[32 + lhi*4];

  const int NMT = (T + 15) >> 4;
  for (int mt = w; mt < NMT; mt += 4) {
    const int t0 = mt * 16;
    f16x8 hbf[4];
    #pragma unroll
    for (int q = 0; q < 4; ++q)
      hbf[q] = *(const f16x8*)(hist + ((size_t)b*T + t0 + l16)*H + q*32 + lhi*8);
    f32x4 d0 = {0,0,0,0}, d1 = {0,0,0,0}, d2 = {0,0,0,0};
    #pragma unroll
    for (int q = 0; q < 4; ++q) {
      f16x8 wq0 = *(const f16x8*)tptrc((const f16*)WqH, l16,      q*64 + lhi*16);
      f16x8 wq1 = *(const f16x8*)tptrc((const f16*)WqH, 16 + l16, q*64 + lhi*16);
      f16x8 wq2 = *(const f16x8*)tptrc((const f16*)WqH, 32 + l16, q*64 + lhi*16);
      d0 = __builtin_amdgcn_mfma_f32_16x16x32_f16(wq0, hbf[q], d0, 0,0,0);
      d1 = __builtin_amdgcn_mfma_f32_16x16x32_f16(wq1, hbf[q], d1, 0,0,0);
      d2 = __builtin_amdgcn_mfma_f32_16x16x32_f16(wq2, hbf[q], d2, 0,0,0);
    }
    float p = 0.f;
    #pragma unroll
    for (int i = 0; i < 4; ++i) {
      p += w2v0[i] * sigmoidf_(d0[i] + qcv0[i]);
      p += w2v1[i] * sigmoidf_(d1[i] + qcv1[i]);
      p += w2v2[i] * sigmoidf_(d2[i] + qcv2[i]);
    }
    p += __shfl_xor(p, 16, 64);
    p += __shfl_xor(p, 32, 64);
    if (lhi == 0) logitsS[t0 + l16] = p;
  }
  __syncthreads();

  const int t = tid;
  float logit = -1e30f; int mk = 0;
  if (t < T) {
    mk = mask[(size_t)b*T + t];
    logit = (mk > 0) ? (logitsS[t] + b2[0]) : -1e30f;
  }
  red[tid] = logit; __syncthreads();
  for (int s = 128; s > 0; s >>= 1) { if (tid < s) red[tid] = fmaxf(red[tid], red[tid+s]); __syncthreads(); }
  float mx = red[0]; __syncthreads();
  float ev = (t < T && mk > 0) ? __expf(logit - mx) : 0.f;
  red[tid] = ev; __syncthreads();
  for (int s = 128; s > 0; s >>= 1) { if (tid < s) red[tid] += red[tid+s]; __syncthreads(); }
  float sm = red[0];
  if (t < T) attv[(size_t)b*T + t] = ev / sm;
}

// ---------------- host ----------------
extern "C" void kernel_launch(void* const* d_in, const int* in_sizes, int n_in,
                              void* d_out, int out_size, void* d_ws, size_t ws_size,
                              hipStream_t stream)
{
  const float* query = (const float*)d_in[0];
  const float* ub    = (const float*)d_in[1];
  const int*   mask  = (const int*)d_in[2];
  const float* gWih  = (const float*)d_in[3];
  const float* gWhh  = (const float*)d_in[4];
  const float* gbih  = (const float*)d_in[5];
  const float* gbhh  = (const float*)d_in[6];
  const float* aW1   = (const float*)d_in[7];
  const float* ab1   = (const float*)d_in[8];
  const float* aW2   = (const float*)d_in[9];
  const float* ab2   = (const float*)d_in[10];
  const float* uWih  = (const float*)d_in[11];
  const float* uWhh  = (const float*)d_in[12];
  const float* ubih  = (const float*)d_in[13];
  const float* ubhh  = (const float*)d_in[14];

  const int B    = in_sizes[0] / H;           // 1024
  const int T    = in_sizes[1] / in_sizes[0]; // 200
  const int Bblk = B / 16;                    // 64

  // workspace layout (all offsets 256B-aligned)
  char*  ws   = (char*)d_ws;
  f16*   wf   = (f16*)ws;                                       // 4*384*128 f16 = 393216 B
  int*   lenp = (int*)(ws + 393216);                            // 4096 B
  float* attb = (float*)(ws + 397312);                          // B*T*4 = 819200 B
  f16*   hist = (f16*)(ws + 1216512);                           // B*T*H*2 = 52428800 B
  f16*   gx   = (f16*)(ws + 53645312);                          // T*B*3H*2 = 157286400 B (shared gx0/gx1)

  prep_weights<<<(4*G3*H + 255)/256, 256, 0, stream>>>(gWih, gWhh, uWih, uWhh, wf);
  prep_len<<<(B + 255)/256, 256, 0, stream>>>(mask, lenp, T, B);

  // gx0 = user_behavior @ gWih^T + gbih
  gx_gemm<false><<<dim3(Bblk, 8), 512, 0, stream>>>(ub, (const f16*)nullptr,
      wf, gbih, gx, T, Bblk);

  // GRU scan (writes hist)
  scan_kernel<false><<<Bblk, 512, 0, stream>>>(gx, wf + G3*H, gbhh,
      (const float*)nullptr, (const int*)nullptr, hist, (float*)nullptr, T, Bblk);

  attn_kernel<<<B, 256, 0, stream>>>(query, hist, mask, aW1, ab1, aW2, ab2, attb, T);

  // gx1 = hist @ uWih^T + ubih (reuse gx buffer)
  gx_gemm<true><<<dim3(Bblk, 8), 512, 0, stream>>>((const float*)nullptr, hist,
      wf + 2*G3*H, ubih, gx, T, Bblk);

  // AUGRU scan (writes d_out)
  scan_kernel<true><<<Bblk, 512, 0, stream>>>(gx, wf + 3*G3*H, ubhh,
      attb, lenp, (f16*)nullptr, (float*)d_out, T, Bblk);
}

// Round 6
// 539.482 us; speedup vs baseline: 1.3170x; 1.3170x over previous
//
#include <hip/hip_runtime.h>

typedef _Float16 f16;
typedef _Float16 f16x8 __attribute__((ext_vector_type(8)));
typedef _Float16 f16x4 __attribute__((ext_vector_type(4)));
typedef float    f32x4 __attribute__((ext_vector_type(4)));

#define H  128
#define G3 384
#define AH 36

__device__ __forceinline__ float sigmoidf_(float x){ return 1.f/(1.f+__expf(-x)); }
__device__ __forceinline__ float tanhf_(float x){ return 2.f/(1.f+__expf(-2.f*x)) - 1.f; }

// LDS-only barrier: drain LDS ops, then s_barrier. Global prefetch loads
// stay in flight across it (they'd be drained by __syncthreads' vmcnt(0)).
__device__ __forceinline__ void lds_sync(){
  asm volatile("s_waitcnt lgkmcnt(0)" ::: "memory");
  __builtin_amdgcn_s_barrier();
  asm volatile("" ::: "memory");
}

// swizzled LDS accessor for [16][128] f16 tiles, 256B rows (proven R1/R3)
__device__ __forceinline__ f16* tptr(f16* base, int row, int kbyte){
  return (f16*)((char*)base + row*256 + (kbyte ^ ((row & 7) << 4)));
}
__device__ __forceinline__ const f16* tptrc(const f16* base, int row, int kbyte){
  return (const f16*)((const char*)base + row*256 + (kbyte ^ ((row & 7) << 4)));
}

// ---------------- prep: weights fp32 -> fp16, lengths ----------------
__global__ void prep_weights(const float* __restrict__ a, const float* __restrict__ b,
                             const float* __restrict__ c, const float* __restrict__ d,
                             f16* __restrict__ dst)
{
  int i = blockIdx.x * 256 + threadIdx.x;
  if (i >= 4 * G3 * H) return;
  int m = i / (G3 * H), j = i % (G3 * H);
  const float* s = (m == 0) ? a : (m == 1) ? b : (m == 2) ? c : d;
  dst[i] = (f16)s[j];
}

__global__ void prep_len(const int* __restrict__ mask, int* __restrict__ len, int T, int B)
{
  int b = blockIdx.x * 256 + threadIdx.x;
  if (b >= B) return;
  int s = 0;
  for (int t = 0; t < T; ++t) s += (mask[(size_t)b * T + t] > 0);
  len[b] = s;
}

// ---------------- fused GRU / AUGRU scan (v4) ----------------
// One block = 16 batch rows, 8 waves; wave w owns gate/hidden cols [16w,16w+16).
// waves_per_eu(2,2): occupancy is hard-capped at what our 64-block grid can use,
// so the allocator has no reason to remat/spill the 24 pinned weight frags.
template<bool AUG>
__global__ __launch_bounds__(512)
__attribute__((amdgpu_waves_per_eu(2, 2)))
void scan_kernel(const float* __restrict__ xf32,  // GRU input  [B,T,H] f32
                 const f16*   __restrict__ xf16,  // AUGRU input (hist) [B,T,H] f16
                 const f16*   __restrict__ Wih,   // [3H][H] f16
                 const f16*   __restrict__ Whh,   // [3H][H] f16
                 const float* __restrict__ bih,
                 const float* __restrict__ bhh,
                 const float* __restrict__ att,   // [B,T] (AUG)
                 const int*   __restrict__ len,   // [B]   (AUG)
                 f16*         __restrict__ histo, // [B,T,H] f16 (GRU)
                 float*       __restrict__ outp,  // [B,H]       (AUG)
                 int T)
{
  __shared__ f16  xs[2][16 * H];
  __shared__ f16  hs[2][16 * H];

  const int tid = threadIdx.x;
  const int w   = tid >> 6;
  const int l   = tid & 63;
  const int l16 = l & 15;
  const int lhi = l >> 4;
  const int b0  = blockIdx.x * 16;
  const int colb = w * 16;
  const int c4   = colb + lhi * 4;
  const int srow = tid >> 5, cc = tid & 31;

  // Weight fragments (24 x f16x8 = 96 VGPR), pinned non-remat.
  f16x8 wih[3][4], whh[3][4];
  #pragma unroll
  for (int g = 0; g < 3; ++g)
    #pragma unroll
    for (int q = 0; q < 4; ++q) {
      int off = (g * H + colb + l16) * H + q * 32 + lhi * 8;
      wih[g][q] = *(const f16x8*)(Wih + off);
      whh[g][q] = *(const f16x8*)(Whh + off);
    }
  #pragma unroll
  for (int g = 0; g < 3; ++g)
    #pragma unroll
    for (int q = 0; q < 4; ++q)
      asm volatile("" : "+v"(wih[g][q]), "+v"(whh[g][q]));

  // bias vectors for the lane's 4 cols (MFMA C-init)
  f32x4 bR  = *(const f32x4*)(bih + c4);
  { f32x4 t2 = *(const f32x4*)(bhh + c4);      bR  += t2; }
  f32x4 bZ  = *(const f32x4*)(bih + H + c4);
  { f32x4 t2 = *(const f32x4*)(bhh + H + c4);  bZ  += t2; }
  f32x4 bXn = *(const f32x4*)(bih + 2*H + c4);
  f32x4 bHn = *(const f32x4*)(bhh + 2*H + c4);

  float hold[4] = {0.f, 0.f, 0.f, 0.f};
  int len_l = 0;
  if (AUG) len_l = len[b0 + l16];

  // running pointers (strength-reduced in-loop addressing)
  const float* pxA32 = xf32 ? (xf32 + ((size_t)(b0 + srow) * T) * H + cc * 4) : nullptr;
  const f16*   pxA16 = xf16 ? (xf16 + ((size_t)(b0 + srow) * T) * H + cc * 4) : nullptr;
  const float* attB  = AUG ? (att + (size_t)(b0 + l16) * T) : nullptr;
  f16*         histp = (!AUG && histo) ? (histo + ((size_t)(b0 + l16) * T) * H + c4) : nullptr;
  float*       outpp = AUG ? (outp + (size_t)(b0 + l16) * H + c4) : nullptr;

  // prologue: zero h buf 0, stage x_0, prefetch x_1 into Pa
  {
    f16x4 z4 = {(f16)0, (f16)0, (f16)0, (f16)0};
    *(f16x4*)tptr(hs[0], srow, cc * 8) = z4;
    if (AUG) {
      f16x4 v = *(const f16x4*)(pxA16);
      *(f16x4*)tptr(xs[0], srow, cc * 8) = v;
    } else {
      f32x4 v = *(const f32x4*)(pxA32);
      f16x4 h4 = {(f16)v.x, (f16)v.y, (f16)v.z, (f16)v.w};
      *(f16x4*)tptr(xs[0], srow, cc * 8) = h4;
    }
  }
  f32x4 Pa32 = {0,0,0,0}, Pb32 = {0,0,0,0};
  f16x4 Pa16 = {(f16)0,(f16)0,(f16)0,(f16)0}, Pb16 = Pa16;
  float Aa = 0.f, Ab = 0.f;
  if (AUG) {
    Pa16 = *(const f16x4*)(pxA16 + H);
    Aa = attB[0];
    if (T > 1) Ab = attB[1];
  } else {
    Pa32 = *(const f32x4*)(pxA32 + H);
  }
  // in-loop prefetch pointers: even steps load x[t+2] (even idx) via pxE,
  // odd steps via pxO. Each advances 2 timesteps after use.
  const float* pxE32 = pxA32 ? pxA32 + 2 * H : nullptr;
  const float* pxO32 = pxA32 ? pxA32 + 3 * H : nullptr;
  const f16*   pxE16 = pxA16 ? pxA16 + 2 * H : nullptr;
  const f16*   pxO16 = pxA16 ? pxA16 + 3 * H : nullptr;
  lds_sync();

// macro-internal names suffixed; PW/PL are ping-pong regs, PXP the parity pointer.
#define STEP(targ_, PW32, PL32, PW16, PL16, AW, PXP32, PXP16)                  \
  {                                                                            \
    const int t5_  = (targ_);                                                  \
    const int cur_ = t5_ & 1, nxt_ = cur_ ^ 1;                                 \
    float at_ = 0.f;                                                           \
    if (AUG) at_ = AW;                                                         \
    if (t5_ + 2 < T) {                                                         \
      if (AUG) {                                                               \
        PL16 = *(const f16x4*)(PXP16);  PXP16 += 2 * H;                        \
        AW = attB[t5_ + 2];                                                    \
      } else {                                                                 \
        PL32 = *(const f32x4*)(PXP32);  PXP32 += 2 * H;                        \
      }                                                                        \
    }                                                                          \
    f16x8 xb[4], hb[4];                                                        \
    _Pragma("unroll")                                                          \
    for (int q = 0; q < 4; ++q) {                                              \
      xb[q] = *(const f16x8*)tptrc((const f16*)xs[cur_], l16, q*64 + lhi*16);  \
      hb[q] = *(const f16x8*)tptrc((const f16*)hs[cur_], l16, q*64 + lhi*16);  \
    }                                                                          \
    f32x4 aR = bR, aZ = bZ, aXn = bXn, aHn = bHn;                              \
    _Pragma("unroll")                                                          \
    for (int q = 0; q < 4; ++q) {                                              \
      aR  = __builtin_amdgcn_mfma_f32_16x16x32_f16(wih[0][q], xb[q], aR, 0,0,0);  \
      aZ  = __builtin_amdgcn_mfma_f32_16x16x32_f16(wih[1][q], xb[q], aZ, 0,0,0);  \
      aXn = __builtin_amdgcn_mfma_f32_16x16x32_f16(wih[2][q], xb[q], aXn,0,0,0);  \
      aHn = __builtin_amdgcn_mfma_f32_16x16x32_f16(whh[2][q], hb[q], aHn,0,0,0);  \
    }                                                                          \
    _Pragma("unroll")                                                          \
    for (int q = 0; q < 4; ++q) {                                              \
      aR  = __builtin_amdgcn_mfma_f32_16x16x32_f16(whh[0][q], hb[q], aR, 0,0,0);  \
      aZ  = __builtin_amdgcn_mfma_f32_16x16x32_f16(whh[1][q], hb[q], aZ, 0,0,0);  \
    }                                                                          \
    float hn_[4];                                                              \
    _Pragma("unroll")                                                          \
    for (int i = 0; i < 4; ++i) {                                              \
      float r = sigmoidf_(aR[i]);                                              \
      float z = sigmoidf_(aZ[i]);                                              \
      float n = tanhf_(aXn[i] + r * aHn[i]);                                   \
      float h;                                                                 \
      if (AUG) { float u = z * at_; h = hold[i] + u * (n - hold[i]); }         \
      else     { h = n + z * (hold[i] - n); }                                  \
      hold[i] = h; hn_[i] = h;                                                 \
    }                                                                          \
    f16x4 hv = {(f16)hn_[0], (f16)hn_[1], (f16)hn_[2], (f16)hn_[3]};           \
    *(f16x4*)tptr(hs[nxt_], l16, 2 * c4) = hv;                                 \
    if (!AUG) {                                                                \
      *(f16x4*)histp = hv;  histp += H;                                        \
    } else {                                                                   \
      if (t5_ == len_l - 1) {                                                  \
        f32x4 ov = {hn_[0], hn_[1], hn_[2], hn_[3]};                           \
        *(f32x4*)outpp = ov;                                                   \
      }                                                                        \
    }                                                                          \
    if (t5_ + 1 < T) {                                                         \
      if (AUG) {                                                               \
        *(f16x4*)tptr(xs[nxt_], srow, cc * 8) = PW16;                          \
      } else {                                                                 \
        f16x4 s4 = {(f16)PW32.x, (f16)PW32.y, (f16)PW32.z, (f16)PW32.w};       \
        *(f16x4*)tptr(xs[nxt_], srow, cc * 8) = s4;                            \
      }                                                                        \
    }                                                                          \
    lds_sync();                                                                \
  }

  for (int t = 0; t < T; t += 2) {
    STEP(t,     Pa32, Pb32, Pa16, Pb16, Aa, pxE32, pxE16)
    STEP(t + 1, Pb32, Pa32, Pb16, Pa16, Ab, pxO32, pxO16)
  }
#undef STEP
}

// ---------------- DIN attention (MFMA version, proven R5) ----------------
__global__ __launch_bounds__(256)
void attn_kernel(const float* __restrict__ query,
                 const f16*   __restrict__ hist,
                 const int*   __restrict__ mask,
                 const float* __restrict__ W1, const float* __restrict__ b1,
                 const float* __restrict__ W2, const float* __restrict__ b2,
                 float* __restrict__ attv, int T)
{
  __shared__ float qs[H];
  __shared__ f16   WqH[48 * H];
  __shared__ float qcp[48], w2p[48];
  __shared__ float logitsS[224];
  __shared__ float red[256];

  const int tid = threadIdx.x, b = blockIdx.x;
  const int w = tid >> 6, l = tid & 63, l16 = l & 15, lhi = l >> 4;

  if (tid < H) qs[tid] = query[b * H + tid];
  if (tid < 48) w2p[tid] = (tid < AH) ? W2[tid] : 0.f;
  __syncthreads();

  for (int i = tid; i < 48 * H; i += 256) {
    int u = i >> 7, k = i & (H - 1);
    float v = 0.f;
    if (u < AH) {
      const float* r = W1 + u * 4 * H;
      v = r[H + k] - r[2*H + k] + qs[k] * r[3*H + k];
    }
    *tptr((f16*)WqH, u, 2 * k) = (f16)v;
  }
  if (tid < 48) {
    float s = 0.f;
    if (tid < AH) {
      const float* r = W1 + tid * 4 * H;
      s = b1[tid];
      for (int k = 0; k < H; ++k) s += qs[k] * (r[k] + r[2*H + k]);
    }
    qcp[tid] = s;
  }
  __syncthreads();

  const f32x4 qcv0 = *(const f32x4*)&qcp[lhi*4];
  const f32x4 qcv1 = *(const f32x4*)&qcp[16 + lhi*4];
  const f32x4 qcv2 = *(const f32x4*)&qcp[32 + lhi*4];
  const f32x4 w2v0 = *(const f32x4*)&w2p[lhi*4];
  const f32x4 w2v1 = *(const f32x4*)&w2p[16 + lhi*4];
  const f32x4 w2v2 = *(const f32x4*)&w2p[32 + lhi*4];

  const int NMT = (T + 15) >> 4;
  for (int mt = w; mt < NMT; mt += 4) {
    const int t0 = mt * 16;
    f16x8 hbf[4];
    #pragma unroll
    for (int q = 0; q < 4; ++q)
      hbf[q] = *(const f16x8*)(hist + ((size_t)b*T + t0 + l16)*H + q*32 + lhi*8);
    f32x4 d0 = {0,0,0,0}, d1 = {0,0,0,0}, d2 = {0,0,0,0};
    #pragma unroll
    for (int q = 0; q < 4; ++q) {
      f16x8 wq0 = *(const f16x8*)tptrc((const f16*)WqH, l16,      q*64 + lhi*16);
      f16x8 wq1 = *(const f16x8*)tptrc((const f16*)WqH, 16 + l16, q*64 + lhi*16);
      f16x8 wq2 = *(const f16x8*)tptrc((const f16*)WqH, 32 + l16, q*64 + lhi*16);
      d0 = __builtin_amdgcn_mfma_f32_16x16x32_f16(wq0, hbf[q], d0, 0,0,0);
      d1 = __builtin_amdgcn_mfma_f32_16x16x32_f16(wq1, hbf[q], d1, 0,0,0);
      d2 = __builtin_amdgcn_mfma_f32_16x16x32_f16(wq2, hbf[q], d2, 0,0,0);
    }
    float p = 0.f;
    #pragma unroll
    for (int i = 0; i < 4; ++i) {
      p += w2v0[i] * sigmoidf_(d0[i] + qcv0[i]);
      p += w2v1[i] * sigmoidf_(d1[i] + qcv1[i]);
      p += w2v2[i] * sigmoidf_(d2[i] + qcv2[i]);
    }
    p += __shfl_xor(p, 16, 64);
    p += __shfl_xor(p, 32, 64);
    if (lhi == 0) logitsS[t0 + l16] = p;
  }
  __syncthreads();

  const int t = tid;
  float logit = -1e30f; int mk = 0;
  if (t < T) {
    mk = mask[(size_t)b*T + t];
    logit = (mk > 0) ? (logitsS[t] + b2[0]) : -1e30f;
  }
  red[tid] = logit; __syncthreads();
  for (int s = 128; s > 0; s >>= 1) { if (tid < s) red[tid] = fmaxf(red[tid], red[tid+s]); __syncthreads(); }
  float mx = red[0]; __syncthreads();
  float ev = (t < T && mk > 0) ? __expf(logit - mx) : 0.f;
  red[tid] = ev; __syncthreads();
  for (int s = 128; s > 0; s >>= 1) { if (tid < s) red[tid] += red[tid+s]; __syncthreads(); }
  float sm = red[0];
  if (t < T) attv[(size_t)b*T + t] = ev / sm;
}

// ---------------- host ----------------
extern "C" void kernel_launch(void* const* d_in, const int* in_sizes, int n_in,
                              void* d_out, int out_size, void* d_ws, size_t ws_size,
                              hipStream_t stream)
{
  const float* query = (const float*)d_in[0];
  const float* ub    = (const float*)d_in[1];
  const int*   mask  = (const int*)d_in[2];
  const float* gWih  = (const float*)d_in[3];
  const float* gWhh  = (const float*)d_in[4];
  const float* gbih  = (const float*)d_in[5];
  const float* gbhh  = (const float*)d_in[6];
  const float* aW1   = (const float*)d_in[7];
  const float* ab1   = (const float*)d_in[8];
  const float* aW2   = (const float*)d_in[9];
  const float* ab2   = (const float*)d_in[10];
  const float* uWih  = (const float*)d_in[11];
  const float* uWhh  = (const float*)d_in[12];
  const float* ubih  = (const float*)d_in[13];
  const float* ubhh  = (const float*)d_in[14];

  const int B = in_sizes[0] / H;            // 1024
  const int T = in_sizes[1] / in_sizes[0];  // 200

  // workspace layout
  char*  ws   = (char*)d_ws;
  f16*   wf   = (f16*)ws;                                   // 393216 B
  int*   lenp = (int*)(ws + 393216);                        // 4096 B
  float* attb = (float*)(ws + 397312);                      // B*T*4
  f16*   hist = (f16*)(ws + 397312 + (size_t)B * 200 * 4);  // B*T*H f16

  prep_weights<<<(4 * G3 * H + 255) / 256, 256, 0, stream>>>(gWih, gWhh, uWih, uWhh, wf);
  prep_len<<<(B + 255) / 256, 256, 0, stream>>>(mask, lenp, T, B);

  scan_kernel<false><<<B / 16, 512, 0, stream>>>(
      ub, (const f16*)nullptr, wf, wf + G3 * H, gbih, gbhh,
      (const float*)nullptr, (const int*)nullptr, hist, (float*)nullptr, T);

  attn_kernel<<<B, 256, 0, stream>>>(query, hist, mask, aW1, ab1, aW2, ab2, attb, T);

  scan_kernel<true><<<B / 16, 512, 0, stream>>>(
      (const float*)nullptr, hist, wf + 2 * G3 * H, wf + 3 * G3 * H, ubih, ubhh,
      attb, lenp, (f16*)nullptr, (float*)d_out, T);
}

// Round 7
// 539.222 us; speedup vs baseline: 1.3176x; 1.0005x over previous
//
#include <hip/hip_runtime.h>

typedef _Float16 f16;
typedef _Float16 f16x8 __attribute__((ext_vector_type(8)));
typedef _Float16 f16x4 __attribute__((ext_vector_type(4)));
typedef float    f32x4 __attribute__((ext_vector_type(4)));

#define H  128
#define G3 384
#define AH 36

__device__ __forceinline__ float sigmoidf_(float x){ return 1.f/(1.f+__expf(-x)); }
__device__ __forceinline__ float tanhf_(float x){ return 2.f/(1.f+__expf(-2.f*x)) - 1.f; }

// LDS-only barrier: drain LDS ops, then s_barrier. Global prefetch loads
// stay in flight across it (they'd be drained by __syncthreads' vmcnt(0)).
__device__ __forceinline__ void lds_sync(){
  asm volatile("s_waitcnt lgkmcnt(0)" ::: "memory");
  __builtin_amdgcn_s_barrier();
  asm volatile("" ::: "memory");
}

// MFMA with weight operand pinned to AGPR class at the USE site. This makes
// remat-by-reload impossible (would need cross-class reload+accvgpr_write),
// so the 24 weight frags stay register-resident across the 200-step loop.
#define MFMA16_A(acc, wa, bb) \
  asm("v_mfma_f32_16x16x32_f16 %0, %1, %2, %0" : "+v"(acc) : "a"(wa), "v"(bb))

// swizzled LDS accessor for [16][128] f16 tiles, 256B rows (proven R1/R3)
__device__ __forceinline__ f16* tptr(f16* base, int row, int kbyte){
  return (f16*)((char*)base + row*256 + (kbyte ^ ((row & 7) << 4)));
}
__device__ __forceinline__ const f16* tptrc(const f16* base, int row, int kbyte){
  return (const f16*)((const char*)base + row*256 + (kbyte ^ ((row & 7) << 4)));
}

// ---------------- prep: weights fp32 -> fp16, lengths ----------------
__global__ void prep_weights(const float* __restrict__ a, const float* __restrict__ b,
                             const float* __restrict__ c, const float* __restrict__ d,
                             f16* __restrict__ dst)
{
  int i = blockIdx.x * 256 + threadIdx.x;
  if (i >= 4 * G3 * H) return;
  int m = i / (G3 * H), j = i % (G3 * H);
  const float* s = (m == 0) ? a : (m == 1) ? b : (m == 2) ? c : d;
  dst[i] = (f16)s[j];
}

__global__ void prep_len(const int* __restrict__ mask, int* __restrict__ len, int T, int B)
{
  int b = blockIdx.x * 256 + threadIdx.x;
  if (b >= B) return;
  int s = 0;
  for (int t = 0; t < T; ++t) s += (mask[(size_t)b * T + t] > 0);
  len[b] = s;
}

// ---------------- fused GRU / AUGRU scan (v5: AGPR-resident weights) ----------------
template<bool AUG>
__global__ __launch_bounds__(512)
__attribute__((amdgpu_waves_per_eu(2, 2)))
void scan_kernel(const float* __restrict__ xf32,  // GRU input  [B,T,H] f32
                 const f16*   __restrict__ xf16,  // AUGRU input (hist) [B,T,H] f16
                 const f16*   __restrict__ Wih,   // [3H][H] f16
                 const f16*   __restrict__ Whh,   // [3H][H] f16
                 const float* __restrict__ bih,
                 const float* __restrict__ bhh,
                 const float* __restrict__ att,   // [B,T] (AUG)
                 const int*   __restrict__ len,   // [B]   (AUG)
                 f16*         __restrict__ histo, // [B,T,H] f16 (GRU)
                 float*       __restrict__ outp,  // [B,H]       (AUG)
                 int T)
{
  __shared__ f16  xs[2][16 * H];
  __shared__ f16  hs[2][16 * H];

  const int tid = threadIdx.x;
  const int w   = tid >> 6;
  const int l   = tid & 63;
  const int l16 = l & 15;
  const int lhi = l >> 4;
  const int b0  = blockIdx.x * 16;
  const int colb = w * 16;
  const int c4   = colb + lhi * 4;
  const int srow = tid >> 5, cc = tid & 31;

  // Weight fragments -> AGPRs (24 x f16x8 = 96 AGPR).
  f16x8 wih[3][4], whh[3][4];
  #pragma unroll
  for (int g = 0; g < 3; ++g)
    #pragma unroll
    for (int q = 0; q < 4; ++q) {
      int off = (g * H + colb + l16) * H + q * 32 + lhi * 8;
      wih[g][q] = *(const f16x8*)(Wih + off);
      whh[g][q] = *(const f16x8*)(Whh + off);
    }
  #pragma unroll
  for (int g = 0; g < 3; ++g)
    #pragma unroll
    for (int q = 0; q < 4; ++q)
      asm volatile("" : "+a"(wih[g][q]), "+a"(whh[g][q]));   // anchor in AGPR class

  // bias vectors for the lane's 4 cols (accumulator init)
  f32x4 bR  = *(const f32x4*)(bih + c4);
  { f32x4 t2 = *(const f32x4*)(bhh + c4);      bR  += t2; }
  f32x4 bZ  = *(const f32x4*)(bih + H + c4);
  { f32x4 t2 = *(const f32x4*)(bhh + H + c4);  bZ  += t2; }
  f32x4 bXn = *(const f32x4*)(bih + 2*H + c4);
  f32x4 bHn = *(const f32x4*)(bhh + 2*H + c4);

  float hold[4] = {0.f, 0.f, 0.f, 0.f};
  int len_l = 0;
  if (AUG) len_l = len[b0 + l16];

  // running pointers
  const float* pxA32 = xf32 ? (xf32 + ((size_t)(b0 + srow) * T) * H + cc * 4) : nullptr;
  const f16*   pxA16 = xf16 ? (xf16 + ((size_t)(b0 + srow) * T) * H + cc * 4) : nullptr;
  const float* attB  = AUG ? (att + (size_t)(b0 + l16) * T) : nullptr;
  f16*         histp = (!AUG && histo) ? (histo + ((size_t)(b0 + l16) * T) * H + c4) : nullptr;
  float*       outpp = AUG ? (outp + (size_t)(b0 + l16) * H + c4) : nullptr;

  // prologue: zero h buf 0, stage x_0, prefetch x_1 into Pa
  {
    f16x4 z4 = {(f16)0, (f16)0, (f16)0, (f16)0};
    *(f16x4*)tptr(hs[0], srow, cc * 8) = z4;
    if (AUG) {
      f16x4 v = *(const f16x4*)(pxA16);
      *(f16x4*)tptr(xs[0], srow, cc * 8) = v;
    } else {
      f32x4 v = *(const f32x4*)(pxA32);
      f16x4 h4 = {(f16)v.x, (f16)v.y, (f16)v.z, (f16)v.w};
      *(f16x4*)tptr(xs[0], srow, cc * 8) = h4;
    }
  }
  f32x4 Pa32 = {0,0,0,0}, Pb32 = {0,0,0,0};
  f16x4 Pa16 = {(f16)0,(f16)0,(f16)0,(f16)0}, Pb16 = Pa16;
  float Aa = 0.f, Ab = 0.f;
  if (AUG) {
    Pa16 = *(const f16x4*)(pxA16 + H);
    Aa = attB[0];
    if (T > 1) Ab = attB[1];
  } else {
    Pa32 = *(const f32x4*)(pxA32 + H);
  }
  const float* pxE32 = pxA32 ? pxA32 + 2 * H : nullptr;
  const float* pxO32 = pxA32 ? pxA32 + 3 * H : nullptr;
  const f16*   pxE16 = pxA16 ? pxA16 + 2 * H : nullptr;
  const f16*   pxO16 = pxA16 ? pxA16 + 3 * H : nullptr;
  lds_sync();

// macro-internal names suffixed; PW/PL ping-pong regs, PXP parity pointer.
#define STEP(targ_, PW32, PL32, PW16, PL16, AW, PXP32, PXP16)                  \
  {                                                                            \
    const int t5_  = (targ_);                                                  \
    const int cur_ = t5_ & 1, nxt_ = cur_ ^ 1;                                 \
    float at_ = 0.f;                                                           \
    if (AUG) at_ = AW;                                                         \
    if (t5_ + 2 < T) {                                                         \
      if (AUG) {                                                               \
        PL16 = *(const f16x4*)(PXP16);  PXP16 += 2 * H;                        \
        AW = attB[t5_ + 2];                                                    \
      } else {                                                                 \
        PL32 = *(const f32x4*)(PXP32);  PXP32 += 2 * H;                        \
      }                                                                        \
    }                                                                          \
    f16x8 xb[4], hb[4];                                                        \
    _Pragma("unroll")                                                          \
    for (int q = 0; q < 4; ++q) {                                              \
      xb[q] = *(const f16x8*)tptrc((const f16*)xs[cur_], l16, q*64 + lhi*16);  \
      hb[q] = *(const f16x8*)tptrc((const f16*)hs[cur_], l16, q*64 + lhi*16);  \
    }                                                                          \
    f32x4 aR = bR, aZ = bZ, aXn = bXn, aHn = bHn;                              \
    _Pragma("unroll")                                                          \
    for (int q = 0; q < 4; ++q) {                                              \
      MFMA16_A(aR,  wih[0][q], xb[q]);                                         \
      MFMA16_A(aZ,  wih[1][q], xb[q]);                                         \
      MFMA16_A(aXn, wih[2][q], xb[q]);                                         \
      MFMA16_A(aHn, whh[2][q], hb[q]);                                         \
    }                                                                          \
    _Pragma("unroll")                                                          \
    for (int q = 0; q < 4; ++q) {                                              \
      MFMA16_A(aR,  whh[0][q], hb[q]);                                         \
      MFMA16_A(aZ,  whh[1][q], hb[q]);                                         \
    }                                                                          \
    float hn_[4];                                                              \
    _Pragma("unroll")                                                          \
    for (int i = 0; i < 4; ++i) {                                              \
      float r = sigmoidf_(aR[i]);                                              \
      float z = sigmoidf_(aZ[i]);                                              \
      float n = tanhf_(aXn[i] + r * aHn[i]);                                   \
      float h;                                                                 \
      if (AUG) { float u = z * at_; h = hold[i] + u * (n - hold[i]); }         \
      else     { h = n + z * (hold[i] - n); }                                  \
      hold[i] = h; hn_[i] = h;                                                 \
    }                                                                          \
    f16x4 hv = {(f16)hn_[0], (f16)hn_[1], (f16)hn_[2], (f16)hn_[3]};           \
    *(f16x4*)tptr(hs[nxt_], l16, 2 * c4) = hv;                                 \
    if (!AUG) {                                                                \
      *(f16x4*)histp = hv;  histp += H;                                        \
    } else {                                                                   \
      if (t5_ == len_l - 1) {                                                  \
        f32x4 ov = {hn_[0], hn_[1], hn_[2], hn_[3]};                           \
        *(f32x4*)outpp = ov;                                                   \
      }                                                                        \
    }                                                                          \
    if (t5_ + 1 < T) {                                                         \
      if (AUG) {                                                               \
        *(f16x4*)tptr(xs[nxt_], srow, cc * 8) = PW16;                          \
      } else {                                                                 \
        f16x4 s4 = {(f16)PW32.x, (f16)PW32.y, (f16)PW32.z, (f16)PW32.w};       \
        *(f16x4*)tptr(xs[nxt_], srow, cc * 8) = s4;                            \
      }                                                                        \
    }                                                                          \
    lds_sync();                                                                \
  }

  for (int t = 0; t < T; t += 2) {
    STEP(t,     Pa32, Pb32, Pa16, Pb16, Aa, pxE32, pxE16)
    STEP(t + 1, Pb32, Pa32, Pb16, Pa16, Ab, pxO32, pxO16)
  }
#undef STEP
}

// ---------------- DIN attention (MFMA version, proven R5/R6) ----------------
__global__ __launch_bounds__(256)
void attn_kernel(const float* __restrict__ query,
                 const f16*   __restrict__ hist,
                 const int*   __restrict__ mask,
                 const float* __restrict__ W1, const float* __restrict__ b1,
                 const float* __restrict__ W2, const float* __restrict__ b2,
                 float* __restrict__ attv, int T)
{
  __shared__ float qs[H];
  __shared__ f16   WqH[48 * H];
  __shared__ float qcp[48], w2p[48];
  __shared__ float logitsS[224];
  __shared__ float red[256];

  const int tid = threadIdx.x, b = blockIdx.x;
  const int w = tid >> 6, l = tid & 63, l16 = l & 15, lhi = l >> 4;

  if (tid < H) qs[tid] = query[b * H + tid];
  if (tid < 48) w2p[tid] = (tid < AH) ? W2[tid] : 0.f;
  __syncthreads();

  for (int i = tid; i < 48 * H; i += 256) {
    int u = i >> 7, k = i & (H - 1);
    float v = 0.f;
    if (u < AH) {
      const float* r = W1 + u * 4 * H;
      v = r[H + k] - r[2*H + k] + qs[k] * r[3*H + k];
    }
    *tptr((f16*)WqH, u, 2 * k) = (f16)v;
  }
  if (tid < 48) {
    float s = 0.f;
    if (tid < AH) {
      const float* r = W1 + tid * 4 * H;
      s = b1[tid];
      for (int k = 0; k < H; ++k) s += qs[k] * (r[k] + r[2*H + k]);
    }
    qcp[tid] = s;
  }
  __syncthreads();

  const f32x4 qcv0 = *(const f32x4*)&qcp[lhi*4];
  const f32x4 qcv1 = *(const f32x4*)&qcp[16 + lhi*4];
  const f32x4 qcv2 = *(const f32x4*)&qcp[32 + lhi*4];
  const f32x4 w2v0 = *(const f32x4*)&w2p[lhi*4];
  const f32x4 w2v1 = *(const f32x4*)&w2p[16 + lhi*4];
  const f32x4 w2v2 = *(const f32x4*)&w2p[32 + lhi*4];

  const int NMT = (T + 15) >> 4;
  for (int mt = w; mt < NMT; mt += 4) {
    const int t0 = mt * 16;
    f16x8 hbf[4];
    #pragma unroll
    for (int q = 0; q < 4; ++q)
      hbf[q] = *(const f16x8*)(hist + ((size_t)b*T + t0 + l16)*H + q*32 + lhi*8);
    f32x4 d0 = {0,0,0,0}, d1 = {0,0,0,0}, d2 = {0,0,0,0};
    #pragma unroll
    for (int q = 0; q < 4; ++q) {
      f16x8 wq0 = *(const f16x8*)tptrc((const f16*)WqH, l16,      q*64 + lhi*16);
      f16x8 wq1 = *(const f16x8*)tptrc((const f16*)WqH, 16 + l16, q*64 + lhi*16);
      f16x8 wq2 = *(const f16x8*)tptrc((const f16*)WqH, 32 + l16, q*64 + lhi*16);
      d0 = __builtin_amdgcn_mfma_f32_16x16x32_f16(wq0, hbf[q], d0, 0,0,0);
      d1 = __builtin_amdgcn_mfma_f32_16x16x32_f16(wq1, hbf[q], d1, 0,0,0);
      d2 = __builtin_amdgcn_mfma_f32_16x16x32_f16(wq2, hbf[q], d2, 0,0,0);
    }
    float p = 0.f;
    #pragma unroll
    for (int i = 0; i < 4; ++i) {
      p += w2v0[i] * sigmoidf_(d0[i] + qcv0[i]);
      p += w2v1[i] * sigmoidf_(d1[i] + qcv1[i]);
      p += w2v2[i] * sigmoidf_(d2[i] + qcv2[i]);
    }
    p += __shfl_xor(p, 16, 64);
    p += __shfl_xor(p, 32, 64);
    if (lhi == 0) logitsS[t0 + l16] = p;
  }
  __syncthreads();

  const int t = tid;
  float logit = -1e30f; int mk = 0;
  if (t < T) {
    mk = mask[(size_t)b*T + t];
    logit = (mk > 0) ? (logitsS[t] + b2[0]) : -1e30f;
  }
  red[tid] = logit; __syncthreads();
  for (int s = 128; s > 0; s >>= 1) { if (tid < s) red[tid] = fmaxf(red[tid], red[tid+s]); __syncthreads(); }
  float mx = red[0]; __syncthreads();
  float ev = (t < T && mk > 0) ? __expf(logit - mx) : 0.f;
  red[tid] = ev; __syncthreads();
  for (int s = 128; s > 0; s >>= 1) { if (tid < s) red[tid] += red[tid+s]; __syncthreads(); }
  float sm = red[0];
  if (t < T) attv[(size_t)b*T + t] = ev / sm;
}

// ---------------- host ----------------
extern "C" void kernel_launch(void* const* d_in, const int* in_sizes, int n_in,
                              void* d_out, int out_size, void* d_ws, size_t ws_size,
                              hipStream_t stream)
{
  const float* query = (const float*)d_in[0];
  const float* ub    = (const float*)d_in[1];
  const int*   mask  = (const int*)d_in[2];
  const float* gWih  = (const float*)d_in[3];
  const float* gWhh  = (const float*)d_in[4];
  const float* gbih  = (const float*)d_in[5];
  const float* gbhh  = (const float*)d_in[6];
  const float* aW1   = (const float*)d_in[7];
  const float* ab1   = (const float*)d_in[8];
  const float* aW2   = (const float*)d_in[9];
  const float* ab2   = (const float*)d_in[10];
  const float* uWih  = (const float*)d_in[11];
  const float* uWhh  = (const float*)d_in[12];
  const float* ubih  = (const float*)d_in[13];
  const float* ubhh  = (const float*)d_in[14];

  const int B = in_sizes[0] / H;            // 1024
  const int T = in_sizes[1] / in_sizes[0];  // 200

  // workspace layout
  char*  ws   = (char*)d_ws;
  f16*   wf   = (f16*)ws;                                   // 393216 B
  int*   lenp = (int*)(ws + 393216);                        // 4096 B
  float* attb = (float*)(ws + 397312);                      // B*T*4
  f16*   hist = (f16*)(ws + 397312 + (size_t)B * 200 * 4);  // B*T*H f16

  prep_weights<<<(4 * G3 * H + 255) / 256, 256, 0, stream>>>(gWih, gWhh, uWih, uWhh, wf);
  prep_len<<<(B + 255) / 256, 256, 0, stream>>>(mask, lenp, T, B);

  scan_kernel<false><<<B / 16, 512, 0, stream>>>(
      ub, (const f16*)nullptr, wf, wf + G3 * H, gbih, gbhh,
      (const float*)nullptr, (const int*)nullptr, hist, (float*)nullptr, T);

  attn_kernel<<<B, 256, 0, stream>>>(query, hist, mask, aW1, ab1, aW2, ab2, attb, T);

  scan_kernel<true><<<B / 16, 512, 0, stream>>>(
      (const float*)nullptr, hist, wf + 2 * G3 * H, wf + 3 * G3 * H, ubih, ubhh,
      attb, lenp, (f16*)nullptr, (float*)d_out, T);
}

// Round 9
// 530.899 us; speedup vs baseline: 1.3383x; 1.0157x over previous
//
#include <hip/hip_runtime.h>

typedef _Float16 f16;
typedef _Float16 f16x8 __attribute__((ext_vector_type(8)));
typedef _Float16 f16x4 __attribute__((ext_vector_type(4)));
typedef float    f32x4 __attribute__((ext_vector_type(4)));

#define H  128
#define G3 384
#define AH 36
#define PADW 136   // padded LDS row: 136 f16 = 272B -> 4-bank row shift, <=2-way alias

__device__ __forceinline__ float sigmoidf_(float x){ return 1.f/(1.f+__expf(-x)); }
__device__ __forceinline__ float tanhf_(float x){ return 2.f/(1.f+__expf(-2.f*x)) - 1.f; }

// LDS-only barrier: drain LDS ops, then s_barrier. Global prefetch loads
// stay in flight across it.
__device__ __forceinline__ void lds_sync(){
  asm volatile("s_waitcnt lgkmcnt(0)" ::: "memory");
  __builtin_amdgcn_s_barrier();
  asm volatile("" ::: "memory");
}

// ---------------- prep: weights fp32 -> fp16, lengths ----------------
__global__ void prep_weights(const float* __restrict__ a, const float* __restrict__ b,
                             const float* __restrict__ c, const float* __restrict__ d,
                             f16* __restrict__ dst)
{
  int i = blockIdx.x * 256 + threadIdx.x;
  if (i >= 4 * G3 * H) return;
  int m = i / (G3 * H), j = i % (G3 * H);
  const float* s = (m == 0) ? a : (m == 1) ? b : (m == 2) ? c : d;
  dst[i] = (f16)s[j];
}

__global__ void prep_len(const int* __restrict__ mask, int* __restrict__ len, int T, int B)
{
  int b = blockIdx.x * 256 + threadIdx.x;
  if (b >= B) return;
  int s = 0;
  for (int t = 0; t < T; ++t) s += (mask[(size_t)b * T + t] > 0);
  len[b] = s;
}

// ---------------- fused GRU / AUGRU scan (v6: padded LDS, literal parity) ----------------
template<bool AUG>
__global__ __launch_bounds__(512)
__attribute__((amdgpu_waves_per_eu(2, 2)))
void scan_kernel(const float* __restrict__ xf32,  // GRU input  [B,T,H] f32
                 const f16*   __restrict__ xf16,  // AUGRU input (hist) [B,T,H] f16
                 const f16*   __restrict__ Wih,   // [3H][H] f16
                 const f16*   __restrict__ Whh,   // [3H][H] f16
                 const float* __restrict__ bih,
                 const float* __restrict__ bhh,
                 const float* __restrict__ att,   // [B,T] (AUG)
                 const int*   __restrict__ len,   // [B]   (AUG)
                 f16*         __restrict__ histo, // [B,T,H] f16 (GRU)
                 float*       __restrict__ outp,  // [B,H]       (AUG)
                 int T)
{
  __shared__ f16  xs[2][16 * PADW];
  __shared__ f16  hs[2][16 * PADW];

  const int tid = threadIdx.x;
  const int w   = tid >> 6;
  const int l   = tid & 63;
  const int l16 = l & 15;
  const int lhi = l >> 4;
  const int b0  = blockIdx.x * 16;
  const int colb = w * 16;
  const int c4   = colb + lhi * 4;
  const int srow = tid >> 5, cc = tid & 31;

  // Weight fragments (24 x f16x8 = 96 regs), pinned (R6 form; R7 proved equal).
  f16x8 wih[3][4], whh[3][4];
  #pragma unroll
  for (int g = 0; g < 3; ++g)
    #pragma unroll
    for (int q = 0; q < 4; ++q) {
      int off = (g * H + colb + l16) * H + q * 32 + lhi * 8;
      wih[g][q] = *(const f16x8*)(Wih + off);
      whh[g][q] = *(const f16x8*)(Whh + off);
    }
  #pragma unroll
  for (int g = 0; g < 3; ++g)
    #pragma unroll
    for (int q = 0; q < 4; ++q)
      asm volatile("" : "+v"(wih[g][q]), "+v"(whh[g][q]));

  // bias vectors for the lane's 4 cols (accumulator init)
  f32x4 bR  = *(const f32x4*)(bih + c4);
  { f32x4 t2 = *(const f32x4*)(bhh + c4);      bR  += t2; }
  f32x4 bZ  = *(const f32x4*)(bih + H + c4);
  { f32x4 t2 = *(const f32x4*)(bhh + H + c4);  bZ  += t2; }
  f32x4 bXn = *(const f32x4*)(bih + 2*H + c4);
  f32x4 bHn = *(const f32x4*)(bhh + 2*H + c4);

  float hold[4] = {0.f, 0.f, 0.f, 0.f};
  int len_l = 0;
  if (AUG) len_l = len[b0 + l16];

  // hoisted LDS pointers (all loop-invariant; literal parity keeps them so)
  const f16* xrd0 = &xs[0][l16 * PADW + lhi * 8];   // + q*32 at use
  const f16* xrd1 = &xs[1][l16 * PADW + lhi * 8];
  const f16* hrd0 = &hs[0][l16 * PADW + lhi * 8];
  const f16* hrd1 = &hs[1][l16 * PADW + lhi * 8];
  f16* hwr0 = &hs[0][l16 * PADW + c4];
  f16* hwr1 = &hs[1][l16 * PADW + c4];
  f16* xst0 = &xs[0][srow * PADW + cc * 4];
  f16* xst1 = &xs[1][srow * PADW + cc * 4];

  // running global pointers
  const float* pxA32 = xf32 ? (xf32 + ((size_t)(b0 + srow) * T) * H + cc * 4) : nullptr;
  const f16*   pxA16 = xf16 ? (xf16 + ((size_t)(b0 + srow) * T) * H + cc * 4) : nullptr;
  const float* attB  = AUG ? (att + (size_t)(b0 + l16) * T) : nullptr;
  f16*         histp = (!AUG && histo) ? (histo + ((size_t)(b0 + l16) * T) * H + c4) : nullptr;
  float*       outpp = AUG ? (outp + (size_t)(b0 + l16) * H + c4) : nullptr;

  // prologue: zero h buf 0, stage x_0, prefetch x_1 into Pa
  {
    f16x4 z4 = {(f16)0, (f16)0, (f16)0, (f16)0};
    *(f16x4*)(&hs[0][srow * PADW + cc * 4]) = z4;
    if (AUG) {
      f16x4 v = *(const f16x4*)(pxA16);
      *(f16x4*)xst0 = v;
    } else {
      f32x4 v = *(const f32x4*)(pxA32);
      f16x4 h4 = {(f16)v.x, (f16)v.y, (f16)v.z, (f16)v.w};
      *(f16x4*)xst0 = h4;
    }
  }
  f32x4 Pa32 = {0,0,0,0}, Pb32 = {0,0,0,0};
  f16x4 Pa16 = {(f16)0,(f16)0,(f16)0,(f16)0}, Pb16 = Pa16;
  float Aa = 0.f, Ab = 0.f;
  if (AUG) {
    Pa16 = *(const f16x4*)(pxA16 + H);
    Aa = attB[0];
    if (T > 1) Ab = attB[1];
  } else {
    Pa32 = *(const f32x4*)(pxA32 + H);
  }
  const float* pxE32 = pxA32 ? pxA32 + 2 * H : nullptr;
  const float* pxO32 = pxA32 ? pxA32 + 3 * H : nullptr;
  const f16*   pxE16 = pxA16 ? pxA16 + 2 * H : nullptr;
  const f16*   pxO16 = pxA16 ? pxA16 + 3 * H : nullptr;
  lds_sync();

// CUR/NXT are LITERALS (0/1): all LDS addressing resolves to the hoisted
// pointers at compile time. Macro-internal names suffixed (R3 lesson).
#define STEP(targ_, XRD, HRD, HWRN, XSTN, PW32, PL32, PW16, PL16, AW, PXP32, PXP16) \
  {                                                                            \
    const int t5_  = (targ_);                                                  \
    float at_ = 0.f;                                                           \
    if (AUG) at_ = AW;                                                         \
    if (t5_ + 2 < T) {                                                         \
      if (AUG) {                                                               \
        PL16 = *(const f16x4*)(PXP16);  PXP16 += 2 * H;                        \
        AW = attB[t5_ + 2];                                                    \
      } else {                                                                 \
        PL32 = *(const f32x4*)(PXP32);  PXP32 += 2 * H;                        \
      }                                                                        \
    }                                                                          \
    f16x8 xb[4], hb[4];                                                        \
    _Pragma("unroll")                                                          \
    for (int q = 0; q < 4; ++q) {                                              \
      xb[q] = *(const f16x8*)(XRD + q * 32);                                   \
      hb[q] = *(const f16x8*)(HRD + q * 32);                                   \
    }                                                                          \
    f32x4 aR = bR, aZ = bZ, aXn = bXn, aHn = bHn;                              \
    _Pragma("unroll")                                                          \
    for (int q = 0; q < 4; ++q) {                                              \
      aR  = __builtin_amdgcn_mfma_f32_16x16x32_f16(wih[0][q], xb[q], aR, 0,0,0);  \
      aZ  = __builtin_amdgcn_mfma_f32_16x16x32_f16(wih[1][q], xb[q], aZ, 0,0,0);  \
      aXn = __builtin_amdgcn_mfma_f32_16x16x32_f16(wih[2][q], xb[q], aXn,0,0,0);  \
      aHn = __builtin_amdgcn_mfma_f32_16x16x32_f16(whh[2][q], hb[q], aHn,0,0,0);  \
    }                                                                          \
    _Pragma("unroll")                                                          \
    for (int q = 0; q < 4; ++q) {                                              \
      aR  = __builtin_amdgcn_mfma_f32_16x16x32_f16(whh[0][q], hb[q], aR, 0,0,0);  \
      aZ  = __builtin_amdgcn_mfma_f32_16x16x32_f16(whh[1][q], hb[q], aZ, 0,0,0);  \
    }                                                                          \
    float hn_[4];                                                              \
    _Pragma("unroll")                                                          \
    for (int i = 0; i < 4; ++i) {                                              \
      float r = sigmoidf_(aR[i]);                                              \
      float z = sigmoidf_(aZ[i]);                                              \
      float n = tanhf_(aXn[i] + r * aHn[i]);                                   \
      float h;                                                                 \
      if (AUG) { float u = z * at_; h = hold[i] + u * (n - hold[i]); }         \
      else     { h = n + z * (hold[i] - n); }                                  \
      hold[i] = h; hn_[i] = h;                                                 \
    }                                                                          \
    f16x4 hv = {(f16)hn_[0], (f16)hn_[1], (f16)hn_[2], (f16)hn_[3]};           \
    *(f16x4*)(HWRN) = hv;                                                      \
    if (!AUG) {                                                                \
      *(f16x4*)histp = hv;  histp += H;                                        \
    } else {                                                                   \
      if (t5_ == len_l - 1) {                                                  \
        f32x4 ov = {hn_[0], hn_[1], hn_[2], hn_[3]};                           \
        *(f32x4*)outpp = ov;                                                   \
      }                                                                        \
    }                                                                          \
    if (t5_ + 1 < T) {                                                         \
      if (AUG) {                                                               \
        *(f16x4*)(XSTN) = PW16;                                                \
      } else {                                                                 \
        f16x4 s4 = {(f16)PW32.x, (f16)PW32.y, (f16)PW32.z, (f16)PW32.w};       \
        *(f16x4*)(XSTN) = s4;                                                  \
      }                                                                        \
    }                                                                          \
    lds_sync();                                                                \
  }

  for (int t = 0; t < T; t += 2) {
    STEP(t,     xrd0, hrd0, hwr1, xst1, Pa32, Pb32, Pa16, Pb16, Aa, pxE32, pxE16)
    STEP(t + 1, xrd1, hrd1, hwr0, xst0, Pb32, Pa32, Pb16, Pa16, Ab, pxO32, pxO16)
  }
#undef STEP
}

// ---------------- DIN attention (MFMA version, proven R5/R6/R7) ----------------
// Wq stored in padded LDS rows (PADW) — same <=2-way alias property.
__global__ __launch_bounds__(256)
void attn_kernel(const float* __restrict__ query,
                 const f16*   __restrict__ hist,
                 const int*   __restrict__ mask,
                 const float* __restrict__ W1, const float* __restrict__ b1,
                 const float* __restrict__ W2, const float* __restrict__ b2,
                 float* __restrict__ attv, int T)
{
  __shared__ float qs[H];
  __shared__ f16   WqH[48 * PADW];
  __shared__ float qcp[48], w2p[48];
  __shared__ float logitsS[224];
  __shared__ float red[256];

  const int tid = threadIdx.x, b = blockIdx.x;
  const int w = tid >> 6, l = tid & 63, l16 = l & 15, lhi = l >> 4;

  if (tid < H) qs[tid] = query[b * H + tid];
  if (tid < 48) w2p[tid] = (tid < AH) ? W2[tid] : 0.f;
  __syncthreads();

  for (int i = tid; i < 48 * H; i += 256) {
    int u = i >> 7, k = i & (H - 1);
    float v = 0.f;
    if (u < AH) {
      const float* r = W1 + u * 4 * H;
      v = r[H + k] - r[2*H + k] + qs[k] * r[3*H + k];
    }
    WqH[u * PADW + k] = (f16)v;
  }
  if (tid < 48) {
    float s = 0.f;
    if (tid < AH) {
      const float* r = W1 + tid * 4 * H;
      s = b1[tid];
      for (int k = 0; k < H; ++k) s += qs[k] * (r[k] + r[2*H + k]);
    }
    qcp[tid] = s;
  }
  __syncthreads();

  const f32x4 qcv0 = *(const f32x4*)&qcp[lhi*4];
  const f32x4 qcv1 = *(const f32x4*)&qcp[16 + lhi*4];
  const f32x4 qcv2 = *(const f32x4*)&qcp[32 + lhi*4];
  const f32x4 w2v0 = *(const f32x4*)&w2p[lhi*4];
  const f32x4 w2v1 = *(const f32x4*)&w2p[16 + lhi*4];
  const f32x4 w2v2 = *(const f32x4*)&w2p[32 + lhi*4];

  const int NMT = (T + 15) >> 4;
  for (int mt = w; mt < NMT; mt += 4) {
    const int t0 = mt * 16;
    f16x8 hbf[4];
    #pragma unroll
    for (int q = 0; q < 4; ++q)
      hbf[q] = *(const f16x8*)(hist + ((size_t)b*T + t0 + l16)*H + q*32 + lhi*8);
    f32x4 d0 = {0,0,0,0}, d1 = {0,0,0,0}, d2 = {0,0,0,0};
    #pragma unroll
    for (int q = 0; q < 4; ++q) {
      f16x8 wq0 = *(const f16x8*)(&WqH[ l16       * PADW + q*32 + lhi*8]);
      f16x8 wq1 = *(const f16x8*)(&WqH[(16 + l16) * PADW + q*32 + lhi*8]);
      f16x8 wq2 = *(const f16x8*)(&WqH[(32 + l16) * PADW + q*32 + lhi*8]);
      d0 = __builtin_amdgcn_mfma_f32_16x16x32_f16(wq0, hbf[q], d0, 0,0,0);
      d1 = __builtin_amdgcn_mfma_f32_16x16x32_f16(wq1, hbf[q], d1, 0,0,0);
      d2 = __builtin_amdgcn_mfma_f32_16x16x32_f16(wq2, hbf[q], d2, 0,0,0);
    }
    float p = 0.f;
    #pragma unroll
    for (int i = 0; i < 4; ++i) {
      p += w2v0[i] * sigmoidf_(d0[i] + qcv0[i]);
      p += w2v1[i] * sigmoidf_(d1[i] + qcv1[i]);
      p += w2v2[i] * sigmoidf_(d2[i] + qcv2[i]);
    }
    p += __shfl_xor(p, 16, 64);
    p += __shfl_xor(p, 32, 64);
    if (lhi == 0) logitsS[t0 + l16] = p;
  }
  __syncthreads();

  const int t = tid;
  float logit = -1e30f; int mk = 0;
  if (t < T) {
    mk = mask[(size_t)b*T + t];
    logit = (mk > 0) ? (logitsS[t] + b2[0]) : -1e30f;
  }
  red[tid] = logit; __syncthreads();
  for (int s = 128; s > 0; s >>= 1) { if (tid < s) red[tid] = fmaxf(red[tid], red[tid+s]); __syncthreads(); }
  float mx = red[0]; __syncthreads();
  float ev = (t < T && mk > 0) ? __expf(logit - mx) : 0.f;
  red[tid] = ev; __syncthreads();
  for (int s = 128; s > 0; s >>= 1) { if (tid < s) red[tid] += red[tid+s]; __syncthreads(); }
  float sm = red[0];
  if (t < T) attv[(size_t)b*T + t] = ev / sm;
}

// ---------------- host ----------------
extern "C" void kernel_launch(void* const* d_in, const int* in_sizes, int n_in,
                              void* d_out, int out_size, void* d_ws, size_t ws_size,
                              hipStream_t stream)
{
  const float* query = (const float*)d_in[0];
  const float* ub    = (const float*)d_in[1];
  const int*   mask  = (const int*)d_in[2];
  const float* gWih  = (const float*)d_in[3];
  const float* gWhh  = (const float*)d_in[4];
  const float* gbih  = (const float*)d_in[5];
  const float* gbhh  = (const float*)d_in[6];
  const float* aW1   = (const float*)d_in[7];
  const float* ab1   = (const float*)d_in[8];
  const float* aW2   = (const float*)d_in[9];
  const float* ab2   = (const float*)d_in[10];
  const float* uWih  = (const float*)d_in[11];
  const float* uWhh  = (const float*)d_in[12];
  const float* ubih  = (const float*)d_in[13];
  const float* ubhh  = (const float*)d_in[14];

  const int B = in_sizes[0] / H;            // 1024
  const int T = in_sizes[1] / in_sizes[0];  // 200

  // workspace layout
  char*  ws   = (char*)d_ws;
  f16*   wf   = (f16*)ws;                                   // 393216 B
  int*   lenp = (int*)(ws + 393216);                        // 4096 B
  float* attb = (float*)(ws + 397312);                      // B*T*4
  f16*   hist = (f16*)(ws + 397312 + (size_t)B * 200 * 4);  // B*T*H f16

  prep_weights<<<(4 * G3 * H + 255) / 256, 256, 0, stream>>>(gWih, gWhh, uWih, uWhh, wf);
  prep_len<<<(B + 255) / 256, 256, 0, stream>>>(mask, lenp, T, B);

  scan_kernel<false><<<B / 16, 512, 0, stream>>>(
      ub, (const f16*)nullptr, wf, wf + G3 * H, gbih, gbhh,
      (const float*)nullptr, (const int*)nullptr, hist, (float*)nullptr, T);

  attn_kernel<<<B, 256, 0, stream>>>(query, hist, mask, aW1, ab1, aW2, ab2, attb, T);

  scan_kernel<true><<<B / 16, 512, 0, stream>>>(
      (const float*)nullptr, hist, wf + 2 * G3 * H, wf + 3 * G3 * H, ubih, ubhh,
      attb, lenp, (f16*)nullptr, (float*)d_out, T);
}

// Round 10
// 367.484 us; speedup vs baseline: 1.9334x; 1.4447x over previous
//
#include <hip/hip_runtime.h>

typedef _Float16 f16;
typedef _Float16 f16x8 __attribute__((ext_vector_type(8)));
typedef _Float16 f16x4 __attribute__((ext_vector_type(4)));
typedef float    f32x4 __attribute__((ext_vector_type(4)));

#define H  128
#define G3 384
#define AH 36
#define PADW 136   // padded LDS row: 136 f16 = 272B

// v_rcp_f32 (~1 ulp) instead of IEEE division: without -ffast-math the
// compiler emits div_scale/div_fmas/div_fixup (~9 VALU) per 1/(1+e) —
// 12 of those per lane per scan step was the hidden VALU bloat.
__device__ __forceinline__ float sigmoidf_(float x){
  return __builtin_amdgcn_rcpf(1.f + __expf(-x));
}
__device__ __forceinline__ float tanhf_(float x){
  return fmaf(2.f, __builtin_amdgcn_rcpf(1.f + __expf(-2.f*x)), -1.f);
}

// LDS-only barrier: drain LDS ops, then s_barrier. Global prefetch loads
// stay in flight across it.
__device__ __forceinline__ void lds_sync(){
  asm volatile("s_waitcnt lgkmcnt(0)" ::: "memory");
  __builtin_amdgcn_s_barrier();
  asm volatile("" ::: "memory");
}

// ---------------- prep: weights fp32 -> fp16, lengths ----------------
__global__ void prep_weights(const float* __restrict__ a, const float* __restrict__ b,
                             const float* __restrict__ c, const float* __restrict__ d,
                             f16* __restrict__ dst)
{
  int i = blockIdx.x * 256 + threadIdx.x;
  if (i >= 4 * G3 * H) return;
  int m = i / (G3 * H), j = i % (G3 * H);
  const float* s = (m == 0) ? a : (m == 1) ? b : (m == 2) ? c : d;
  dst[i] = (f16)s[j];
}

__global__ void prep_len(const int* __restrict__ mask, int* __restrict__ len, int T, int B)
{
  int b = blockIdx.x * 256 + threadIdx.x;
  if (b >= B) return;
  int s = 0;
  for (int t = 0; t < T; ++t) s += (mask[(size_t)b * T + t] > 0);
  len[b] = s;
}

// ---------------- fused GRU / AUGRU scan (v7: R9 + rcp gates) ----------------
template<bool AUG>
__global__ __launch_bounds__(512)
__attribute__((amdgpu_waves_per_eu(2, 2)))
void scan_kernel(const float* __restrict__ xf32,  // GRU input  [B,T,H] f32
                 const f16*   __restrict__ xf16,  // AUGRU input (hist) [B,T,H] f16
                 const f16*   __restrict__ Wih,   // [3H][H] f16
                 const f16*   __restrict__ Whh,   // [3H][H] f16
                 const float* __restrict__ bih,
                 const float* __restrict__ bhh,
                 const float* __restrict__ att,   // [B,T] (AUG)
                 const int*   __restrict__ len,   // [B]   (AUG)
                 f16*         __restrict__ histo, // [B,T,H] f16 (GRU)
                 float*       __restrict__ outp,  // [B,H]       (AUG)
                 int T)
{
  __shared__ f16  xs[2][16 * PADW];
  __shared__ f16  hs[2][16 * PADW];

  const int tid = threadIdx.x;
  const int w   = tid >> 6;
  const int l   = tid & 63;
  const int l16 = l & 15;
  const int lhi = l >> 4;
  const int b0  = blockIdx.x * 16;
  const int colb = w * 16;
  const int c4   = colb + lhi * 4;
  const int srow = tid >> 5, cc = tid & 31;

  // Weight fragments (24 x f16x8 = 96 regs), pinned.
  f16x8 wih[3][4], whh[3][4];
  #pragma unroll
  for (int g = 0; g < 3; ++g)
    #pragma unroll
    for (int q = 0; q < 4; ++q) {
      int off = (g * H + colb + l16) * H + q * 32 + lhi * 8;
      wih[g][q] = *(const f16x8*)(Wih + off);
      whh[g][q] = *(const f16x8*)(Whh + off);
    }
  #pragma unroll
  for (int g = 0; g < 3; ++g)
    #pragma unroll
    for (int q = 0; q < 4; ++q)
      asm volatile("" : "+v"(wih[g][q]), "+v"(whh[g][q]));

  // bias vectors for the lane's 4 cols (accumulator init)
  f32x4 bR  = *(const f32x4*)(bih + c4);
  { f32x4 t2 = *(const f32x4*)(bhh + c4);      bR  += t2; }
  f32x4 bZ  = *(const f32x4*)(bih + H + c4);
  { f32x4 t2 = *(const f32x4*)(bhh + H + c4);  bZ  += t2; }
  f32x4 bXn = *(const f32x4*)(bih + 2*H + c4);
  f32x4 bHn = *(const f32x4*)(bhh + 2*H + c4);

  float hold[4] = {0.f, 0.f, 0.f, 0.f};
  int len_l = 0;
  if (AUG) len_l = len[b0 + l16];

  // hoisted LDS pointers
  const f16* xrd0 = &xs[0][l16 * PADW + lhi * 8];
  const f16* xrd1 = &xs[1][l16 * PADW + lhi * 8];
  const f16* hrd0 = &hs[0][l16 * PADW + lhi * 8];
  const f16* hrd1 = &hs[1][l16 * PADW + lhi * 8];
  f16* hwr0 = &hs[0][l16 * PADW + c4];
  f16* hwr1 = &hs[1][l16 * PADW + c4];
  f16* xst0 = &xs[0][srow * PADW + cc * 4];
  f16* xst1 = &xs[1][srow * PADW + cc * 4];

  // running global pointers
  const float* pxA32 = xf32 ? (xf32 + ((size_t)(b0 + srow) * T) * H + cc * 4) : nullptr;
  const f16*   pxA16 = xf16 ? (xf16 + ((size_t)(b0 + srow) * T) * H + cc * 4) : nullptr;
  const float* attB  = AUG ? (att + (size_t)(b0 + l16) * T) : nullptr;
  f16*         histp = (!AUG && histo) ? (histo + ((size_t)(b0 + l16) * T) * H + c4) : nullptr;
  float*       outpp = AUG ? (outp + (size_t)(b0 + l16) * H + c4) : nullptr;

  // prologue: zero h buf 0, stage x_0, prefetch x_1 into Pa
  {
    f16x4 z4 = {(f16)0, (f16)0, (f16)0, (f16)0};
    *(f16x4*)(&hs[0][srow * PADW + cc * 4]) = z4;
    if (AUG) {
      f16x4 v = *(const f16x4*)(pxA16);
      *(f16x4*)xst0 = v;
    } else {
      f32x4 v = *(const f32x4*)(pxA32);
      f16x4 h4 = {(f16)v.x, (f16)v.y, (f16)v.z, (f16)v.w};
      *(f16x4*)xst0 = h4;
    }
  }
  f32x4 Pa32 = {0,0,0,0}, Pb32 = {0,0,0,0};
  f16x4 Pa16 = {(f16)0,(f16)0,(f16)0,(f16)0}, Pb16 = Pa16;
  float Aa = 0.f, Ab = 0.f;
  if (AUG) {
    Pa16 = *(const f16x4*)(pxA16 + H);
    Aa = attB[0];
    if (T > 1) Ab = attB[1];
  } else {
    Pa32 = *(const f32x4*)(pxA32 + H);
  }
  const float* pxE32 = pxA32 ? pxA32 + 2 * H : nullptr;
  const float* pxO32 = pxA32 ? pxA32 + 3 * H : nullptr;
  const f16*   pxE16 = pxA16 ? pxA16 + 2 * H : nullptr;
  const f16*   pxO16 = pxA16 ? pxA16 + 3 * H : nullptr;
  lds_sync();

#define STEP(targ_, XRD, HRD, HWRN, XSTN, PW32, PL32, PW16, PL16, AW, PXP32, PXP16) \
  {                                                                            \
    const int t5_  = (targ_);                                                  \
    float at_ = 0.f;                                                           \
    if (AUG) at_ = AW;                                                         \
    if (t5_ + 2 < T) {                                                         \
      if (AUG) {                                                               \
        PL16 = *(const f16x4*)(PXP16);  PXP16 += 2 * H;                        \
        AW = attB[t5_ + 2];                                                    \
      } else {                                                                 \
        PL32 = *(const f32x4*)(PXP32);  PXP32 += 2 * H;                        \
      }                                                                        \
    }                                                                          \
    f16x8 xb[4], hb[4];                                                        \
    _Pragma("unroll")                                                          \
    for (int q = 0; q < 4; ++q) {                                              \
      xb[q] = *(const f16x8*)(XRD + q * 32);                                   \
      hb[q] = *(const f16x8*)(HRD + q * 32);                                   \
    }                                                                          \
    f32x4 aR = bR, aZ = bZ, aXn = bXn, aHn = bHn;                              \
    _Pragma("unroll")                                                          \
    for (int q = 0; q < 4; ++q) {                                              \
      aR  = __builtin_amdgcn_mfma_f32_16x16x32_f16(wih[0][q], xb[q], aR, 0,0,0);  \
      aZ  = __builtin_amdgcn_mfma_f32_16x16x32_f16(wih[1][q], xb[q], aZ, 0,0,0);  \
      aXn = __builtin_amdgcn_mfma_f32_16x16x32_f16(wih[2][q], xb[q], aXn,0,0,0);  \
      aHn = __builtin_amdgcn_mfma_f32_16x16x32_f16(whh[2][q], hb[q], aHn,0,0,0);  \
    }                                                                          \
    _Pragma("unroll")                                                          \
    for (int q = 0; q < 4; ++q) {                                              \
      aR  = __builtin_amdgcn_mfma_f32_16x16x32_f16(whh[0][q], hb[q], aR, 0,0,0);  \
      aZ  = __builtin_amdgcn_mfma_f32_16x16x32_f16(whh[1][q], hb[q], aZ, 0,0,0);  \
    }                                                                          \
    float hn_[4];                                                              \
    _Pragma("unroll")                                                          \
    for (int i = 0; i < 4; ++i) {                                              \
      float r = sigmoidf_(aR[i]);                                              \
      float z = sigmoidf_(aZ[i]);                                              \
      float n = tanhf_(aXn[i] + r * aHn[i]);                                   \
      float h;                                                                 \
      if (AUG) { float u = z * at_; h = hold[i] + u * (n - hold[i]); }         \
      else     { h = n + z * (hold[i] - n); }                                  \
      hold[i] = h; hn_[i] = h;                                                 \
    }                                                                          \
    f16x4 hv = {(f16)hn_[0], (f16)hn_[1], (f16)hn_[2], (f16)hn_[3]};           \
    *(f16x4*)(HWRN) = hv;                                                      \
    if (!AUG) {                                                                \
      *(f16x4*)histp = hv;  histp += H;                                        \
    } else {                                                                   \
      if (t5_ == len_l - 1) {                                                  \
        f32x4 ov = {hn_[0], hn_[1], hn_[2], hn_[3]};                           \
        *(f32x4*)outpp = ov;                                                   \
      }                                                                        \
    }                                                                          \
    if (t5_ + 1 < T) {                                                         \
      if (AUG) {                                                               \
        *(f16x4*)(XSTN) = PW16;                                                \
      } else {                                                                 \
        f16x4 s4 = {(f16)PW32.x, (f16)PW32.y, (f16)PW32.z, (f16)PW32.w};       \
        *(f16x4*)(XSTN) = s4;                                                  \
      }                                                                        \
    }                                                                          \
    lds_sync();                                                                \
  }

  for (int t = 0; t < T; t += 2) {
    STEP(t,     xrd0, hrd0, hwr1, xst1, Pa32, Pb32, Pa16, Pb16, Aa, pxE32, pxE16)
    STEP(t + 1, xrd1, hrd1, hwr0, xst0, Pb32, Pa32, Pb16, Pa16, Ab, pxO32, pxO16)
  }
#undef STEP
}

// ---------------- DIN attention (MFMA version; rcp sigmoid) ----------------
__global__ __launch_bounds__(256)
void attn_kernel(const float* __restrict__ query,
                 const f16*   __restrict__ hist,
                 const int*   __restrict__ mask,
                 const float* __restrict__ W1, const float* __restrict__ b1,
                 const float* __restrict__ W2, const float* __restrict__ b2,
                 float* __restrict__ attv, int T)
{
  __shared__ float qs[H];
  __shared__ f16   WqH[48 * PADW];
  __shared__ float qcp[48], w2p[48];
  __shared__ float logitsS[224];
  __shared__ float red[256];

  const int tid = threadIdx.x, b = blockIdx.x;
  const int w = tid >> 6, l = tid & 63, l16 = l & 15, lhi = l >> 4;

  if (tid < H) qs[tid] = query[b * H + tid];
  if (tid < 48) w2p[tid] = (tid < AH) ? W2[tid] : 0.f;
  __syncthreads();

  for (int i = tid; i < 48 * H; i += 256) {
    int u = i >> 7, k = i & (H - 1);
    float v = 0.f;
    if (u < AH) {
      const float* r = W1 + u * 4 * H;
      v = r[H + k] - r[2*H + k] + qs[k] * r[3*H + k];
    }
    WqH[u * PADW + k] = (f16)v;
  }
  if (tid < 48) {
    float s = 0.f;
    if (tid < AH) {
      const float* r = W1 + tid * 4 * H;
      s = b1[tid];
      for (int k = 0; k < H; ++k) s += qs[k] * (r[k] + r[2*H + k]);
    }
    qcp[tid] = s;
  }
  __syncthreads();

  const f32x4 qcv0 = *(const f32x4*)&qcp[lhi*4];
  const f32x4 qcv1 = *(const f32x4*)&qcp[16 + lhi*4];
  const f32x4 qcv2 = *(const f32x4*)&qcp[32 + lhi*4];
  const f32x4 w2v0 = *(const f32x4*)&w2p[lhi*4];
  const f32x4 w2v1 = *(const f32x4*)&w2p[16 + lhi*4];
  const f32x4 w2v2 = *(const f32x4*)&w2p[32 + lhi*4];

  const int NMT = (T + 15) >> 4;
  for (int mt = w; mt < NMT; mt += 4) {
    const int t0 = mt * 16;
    f16x8 hbf[4];
    #pragma unroll
    for (int q = 0; q < 4; ++q)
      hbf[q] = *(const f16x8*)(hist + ((size_t)b*T + t0 + l16)*H + q*32 + lhi*8);
    f32x4 d0 = {0,0,0,0}, d1 = {0,0,0,0}, d2 = {0,0,0,0};
    #pragma unroll
    for (int q = 0; q < 4; ++q) {
      f16x8 wq0 = *(const f16x8*)(&WqH[ l16       * PADW + q*32 + lhi*8]);
      f16x8 wq1 = *(const f16x8*)(&WqH[(16 + l16) * PADW + q*32 + lhi*8]);
      f16x8 wq2 = *(const f16x8*)(&WqH[(32 + l16) * PADW + q*32 + lhi*8]);
      d0 = __builtin_amdgcn_mfma_f32_16x16x32_f16(wq0, hbf[q], d0, 0,0,0);
      d1 = __builtin_amdgcn_mfma_f32_16x16x32_f16(wq1, hbf[q], d1, 0,0,0);
      d2 = __builtin_amdgcn_mfma_f32_16x16x32_f16(wq2, hbf[q], d2, 0,0,0);
    }
    float p = 0.f;
    #pragma unroll
    for (int i = 0; i < 4; ++i) {
      p += w2v0[i] * sigmoidf_(d0[i] + qcv0[i]);
      p += w2v1[i] * sigmoidf_(d1[i] + qcv1[i]);
      p += w2v2[i] * sigmoidf_(d2[i] + qcv2[i]);
    }
    p += __shfl_xor(p, 16, 64);
    p += __shfl_xor(p, 32, 64);
    if (lhi == 0) logitsS[t0 + l16] = p;
  }
  __syncthreads();

  const int t = tid;
  float logit = -1e30f; int mk = 0;
  if (t < T) {
    mk = mask[(size_t)b*T + t];
    logit = (mk > 0) ? (logitsS[t] + b2[0]) : -1e30f;
  }
  red[tid] = logit; __syncthreads();
  for (int s = 128; s > 0; s >>= 1) { if (tid < s) red[tid] = fmaxf(red[tid], red[tid+s]); __syncthreads(); }
  float mx = red[0]; __syncthreads();
  float ev = (t < T && mk > 0) ? __expf(logit - mx) : 0.f;
  red[tid] = ev; __syncthreads();
  for (int s = 128; s > 0; s >>= 1) { if (tid < s) red[tid] += red[tid+s]; __syncthreads(); }
  float sm = red[0];
  if (t < T) attv[(size_t)b*T + t] = ev * __builtin_amdgcn_rcpf(sm);
}

// ---------------- host ----------------
extern "C" void kernel_launch(void* const* d_in, const int* in_sizes, int n_in,
                              void* d_out, int out_size, void* d_ws, size_t ws_size,
                              hipStream_t stream)
{
  const float* query = (const float*)d_in[0];
  const float* ub    = (const float*)d_in[1];
  const int*   mask  = (const int*)d_in[2];
  const float* gWih  = (const float*)d_in[3];
  const float* gWhh  = (const float*)d_in[4];
  const float* gbih  = (const float*)d_in[5];
  const float* gbhh  = (const float*)d_in[6];
  const float* aW1   = (const float*)d_in[7];
  const float* ab1   = (const float*)d_in[8];
  const float* aW2   = (const float*)d_in[9];
  const float* ab2   = (const float*)d_in[10];
  const float* uWih  = (const float*)d_in[11];
  const float* uWhh  = (const float*)d_in[12];
  const float* ubih  = (const float*)d_in[13];
  const float* ubhh  = (const float*)d_in[14];

  const int B = in_sizes[0] / H;            // 1024
  const int T = in_sizes[1] / in_sizes[0];  // 200

  // workspace layout
  char*  ws   = (char*)d_ws;
  f16*   wf   = (f16*)ws;                                   // 393216 B
  int*   lenp = (int*)(ws + 393216);                        // 4096 B
  float* attb = (float*)(ws + 397312);                      // B*T*4
  f16*   hist = (f16*)(ws + 397312 + (size_t)B * 200 * 4);  // B*T*H f16

  prep_weights<<<(4 * G3 * H + 255) / 256, 256, 0, stream>>>(gWih, gWhh, uWih, uWhh, wf);
  prep_len<<<(B + 255) / 256, 256, 0, stream>>>(mask, lenp, T, B);

  scan_kernel<false><<<B / 16, 512, 0, stream>>>(
      ub, (const f16*)nullptr, wf, wf + G3 * H, gbih, gbhh,
      (const float*)nullptr, (const int*)nullptr, hist, (float*)nullptr, T);

  attn_kernel<<<B, 256, 0, stream>>>(query, hist, mask, aW1, ab1, aW2, ab2, attb, T);

  scan_kernel<true><<<B / 16, 512, 0, stream>>>(
      (const float*)nullptr, hist, wf + 2 * G3 * H, wf + 3 * G3 * H, ubih, ubhh,
      attb, lenp, (f16*)nullptr, (float*)d_out, T);
}